// Round 1
// baseline (463.743 us; speedup 1.0000x reference)
//
#include <hip/hip_runtime.h>

// ---------------------------------------------------------------------------
// SelfAttention: qkv = X@W + b ; per-head softmax(q k^T * sqrt(64)) @ v
// fp32 in/out. Precision strategy: split-bf16 3-pass MFMA (hi/lo) for the
// projection and Q*K^T (score err sigma ~3e-4), fp32 softmax, bf16 PV.
// ---------------------------------------------------------------------------

#define S_LEN 2048
#define NH    16
#define DH    64
#define DM    1024
#define EW    3072   // NH*(64+64+64)
#define NROWS 4096   // B*S

using f32x4 = __attribute__((ext_vector_type(4))) float;
using bf8   = __attribute__((ext_vector_type(8))) short;   // 8 bf16 (4 VGPRs)
using s4v   = __attribute__((ext_vector_type(4))) short;

static __device__ __forceinline__ short f2bf(float f) {
  union { float f; unsigned u; } a; a.f = f;
  unsigned r = a.u + 0x7fffu + ((a.u >> 16) & 1u);   // RNE
  return (short)(r >> 16);
}
static __device__ __forceinline__ float bf2f(short h) {
  union { float f; unsigned u; } a;
  a.u = ((unsigned)(unsigned short)h) << 16;
  return a.f;
}

// --------------------------- prep: split X into bf16 hi/lo ------------------
__global__ __launch_bounds__(256) void prep_x(const float* __restrict__ X,
                                              short* __restrict__ Xh,
                                              short* __restrict__ Xl) {
  int i = blockIdx.x * 256 + threadIdx.x;              // 1,048,576 float4s
  float4 v = ((const float4*)X)[i];
  s4v h, l;
  h.x = f2bf(v.x); l.x = f2bf(v.x - bf2f(h.x));
  h.y = f2bf(v.y); l.y = f2bf(v.y - bf2f(h.y));
  h.z = f2bf(v.z); l.z = f2bf(v.z - bf2f(h.z));
  h.w = f2bf(v.w); l.w = f2bf(v.w - bf2f(h.w));
  ((s4v*)Xh)[i] = h;
  ((s4v*)Xl)[i] = l;
}

// ------------------- prep: transpose W -> W^T, split hi/lo ------------------
__global__ __launch_bounds__(256) void prep_w(const float* __restrict__ W,
                                              short* __restrict__ Wth,
                                              short* __restrict__ Wtl) {
  __shared__ float t[32][33];
  int n0 = blockIdx.x * 32;
  int k0 = blockIdx.y * 32;
  int tx = threadIdx.x & 31;
  int ty = threadIdx.x >> 5;        // 0..7
#pragma unroll
  for (int i = 0; i < 32; i += 8)
    t[ty + i][tx] = W[(size_t)(k0 + ty + i) * EW + n0 + tx];
  __syncthreads();
#pragma unroll
  for (int i = 0; i < 32; i += 8) {
    float v = t[tx][ty + i];        // k = k0+tx, n = n0+ty+i
    short hi = f2bf(v);
    short lo = f2bf(v - bf2f(hi));
    size_t o = (size_t)(n0 + ty + i) * DM + k0 + tx;
    Wth[o] = hi; Wtl[o] = lo;
  }
}

// --------------------------- projection GEMM --------------------------------
// C(4096x3072) = X(4096x1024) @ W ; 128x128 tile, 4 waves, BK=32, 3-pass MFMA.
// Epilogue scatters to Q(hi/lo, pre-scaled x8), K(hi/lo), V^T(bf16, d-major).
#define BK  32
#define LDK 40   // padded LDS row stride (bf16 elems)

__global__ __launch_bounds__(256) void proj(
    const short* __restrict__ Xh, const short* __restrict__ Xl,
    const short* __restrict__ Wth, const short* __restrict__ Wtl,
    const float* __restrict__ bias,
    short* __restrict__ Qh, short* __restrict__ Ql,
    short* __restrict__ Kh, short* __restrict__ Kl,
    short* __restrict__ Vt) {
  __shared__ short Ah[128 * LDK], Al[128 * LDK], Bh[128 * LDK], Bl[128 * LDK];
  const int tid = threadIdx.x;
  const int lane = tid & 63, w = tid >> 6;
  const int wr = w >> 1, wc = w & 1;
  const int c = lane & 15, g = lane >> 4;
  const int rowBase = blockIdx.x * 128;
  const int colBase = blockIdx.y * 128;

  f32x4 acc[4][4] = {};

  const int r  = tid >> 1;           // 0..127: LDS row this thread stages
  const int k0 = (tid & 1) << 4;     // 0 or 16

  for (int kt = 0; kt < DM; kt += BK) {
    const size_t ga = (size_t)(rowBase + r) * DM + kt + k0;
    const size_t gb = (size_t)(colBase + r) * DM + kt + k0;
    *(bf8*)&Ah[r * LDK + k0]     = *(const bf8*)&Xh[ga];
    *(bf8*)&Ah[r * LDK + k0 + 8] = *(const bf8*)&Xh[ga + 8];
    *(bf8*)&Al[r * LDK + k0]     = *(const bf8*)&Xl[ga];
    *(bf8*)&Al[r * LDK + k0 + 8] = *(const bf8*)&Xl[ga + 8];
    *(bf8*)&Bh[r * LDK + k0]     = *(const bf8*)&Wth[gb];
    *(bf8*)&Bh[r * LDK + k0 + 8] = *(const bf8*)&Wth[gb + 8];
    *(bf8*)&Bl[r * LDK + k0]     = *(const bf8*)&Wtl[gb];
    *(bf8*)&Bl[r * LDK + k0 + 8] = *(const bf8*)&Wtl[gb + 8];
    __syncthreads();

    bf8 ah[4], al4[4], bh[4], bl[4];
#pragma unroll
    for (int m = 0; m < 4; ++m) {
      int ro = (wr * 64 + m * 16 + c) * LDK + g * 8;
      ah[m]  = *(const bf8*)&Ah[ro];
      al4[m] = *(const bf8*)&Al[ro];
    }
#pragma unroll
    for (int n = 0; n < 4; ++n) {
      int ro = (wc * 64 + n * 16 + c) * LDK + g * 8;
      bh[n] = *(const bf8*)&Bh[ro];
      bl[n] = *(const bf8*)&Bl[ro];
    }
#pragma unroll
    for (int m = 0; m < 4; ++m)
#pragma unroll
      for (int n = 0; n < 4; ++n) {
        acc[m][n] = __builtin_amdgcn_mfma_f32_16x16x32_bf16(al4[m], bh[n], acc[m][n], 0, 0, 0);
        acc[m][n] = __builtin_amdgcn_mfma_f32_16x16x32_bf16(ah[m], bl[n], acc[m][n], 0, 0, 0);
        acc[m][n] = __builtin_amdgcn_mfma_f32_16x16x32_bf16(ah[m], bh[n], acc[m][n], 0, 0, 0);
      }
    __syncthreads();
  }

  // epilogue: bias + scatter to per-head Q/K/V layouts
#pragma unroll
  for (int m = 0; m < 4; ++m)
#pragma unroll
    for (int n = 0; n < 4; ++n)
#pragma unroll
      for (int j = 0; j < 4; ++j) {
        int grow = rowBase + wr * 64 + m * 16 + g * 4 + j;   // 0..4095
        int gcol = colBase + wc * 64 + n * 16 + c;           // 0..3071
        float v = acc[m][n][j] + bias[gcol];
        int bb = grow >> 11, s = grow & 2047;
        int h = gcol / 192, e = gcol - h * 192;
        size_t hb = (size_t)(bb * NH + h);
        if (e < DH) {                      // Q: fold in the *sqrt(64) scale
          float q8 = v * 8.0f;
          short hi = f2bf(q8);
          short lo = f2bf(q8 - bf2f(hi));
          size_t idx = (hb * S_LEN + s) * DH + e;
          Qh[idx] = hi; Ql[idx] = lo;
        } else if (e < 2 * DH) {           // K
          short hi = f2bf(v);
          short lo = f2bf(v - bf2f(hi));
          size_t idx = (hb * S_LEN + s) * DH + (e - DH);
          Kh[idx] = hi; Kl[idx] = lo;
        } else {                           // V, transposed [bh][d][s]
          size_t idx = (hb * DH + (e - 2 * DH)) * S_LEN + s;
          Vt[idx] = f2bf(v);
        }
      }
}

// ------------------------------ attention -----------------------------------
// grid (B*H, S/64); 4 independent waves per block, 16 q-rows per wave.
// Flash-style online softmax over 64-key tiles. Scores: 3-pass split-bf16.
__global__ __launch_bounds__(256) void attn(
    const short* __restrict__ Qh, const short* __restrict__ Ql,
    const short* __restrict__ Kh, const short* __restrict__ Kl,
    const short* __restrict__ Vt, float* __restrict__ out) {
  __shared__ short P[4][16 * 72];   // per-wave P^T staging (16 rows x 64, pad 8)
  const int tid = threadIdx.x;
  const int lane = tid & 63, w = tid >> 6;
  const int c = lane & 15, g = lane >> 4;
  const int bh = blockIdx.x;                 // b*16 + h
  const int q0 = blockIdx.y * 64 + w * 16;
  const size_t qkBase = (size_t)bh * S_LEN * DH;
  const size_t vBase  = (size_t)bh * DH * S_LEN;

  bf8 qh[2], ql[2];
#pragma unroll
  for (int kc = 0; kc < 2; ++kc) {
    size_t idx = qkBase + (size_t)(q0 + c) * DH + kc * 32 + g * 8;
    qh[kc] = *(const bf8*)&Qh[idx];
    ql[kc] = *(const bf8*)&Ql[idx];
  }
  float mrun[4], lsum[4];
#pragma unroll
  for (int j = 0; j < 4; ++j) { mrun[j] = -INFINITY; lsum[j] = 0.f; }
  f32x4 o[4] = {};
  short* myP = &P[w][0];

  for (int kv0 = 0; kv0 < S_LEN; kv0 += 64) {
    f32x4 sc[4];
#pragma unroll
    for (int nb = 0; nb < 4; ++nb) {
      f32x4 s = {};
#pragma unroll
      for (int kc = 0; kc < 2; ++kc) {
        size_t kidx = qkBase + (size_t)(kv0 + nb * 16 + c) * DH + kc * 32 + g * 8;
        bf8 kh = *(const bf8*)&Kh[kidx];
        bf8 kl = *(const bf8*)&Kl[kidx];
        s = __builtin_amdgcn_mfma_f32_16x16x32_bf16(ql[kc], kh, s, 0, 0, 0);
        s = __builtin_amdgcn_mfma_f32_16x16x32_bf16(qh[kc], kl, s, 0, 0, 0);
        s = __builtin_amdgcn_mfma_f32_16x16x32_bf16(qh[kc], kh, s, 0, 0, 0);
      }
      sc[nb] = s;
    }
    // online softmax; lane's rows are g*4+j, col c within each 16-key block
#pragma unroll
    for (int j = 0; j < 4; ++j) {
      float t = fmaxf(fmaxf(sc[0][j], sc[1][j]), fmaxf(sc[2][j], sc[3][j]));
      t = fmaxf(t, __shfl_xor(t, 1));
      t = fmaxf(t, __shfl_xor(t, 2));
      t = fmaxf(t, __shfl_xor(t, 4));
      t = fmaxf(t, __shfl_xor(t, 8));
      float mnew = fmaxf(mrun[j], t);
      float scale = __expf(mrun[j] - mnew);   // exp(-inf)=0 on first tile
      mrun[j] = mnew;
      lsum[j] *= scale;
#pragma unroll
      for (int db = 0; db < 4; ++db) o[db][j] *= scale;
      float ps = 0.f;
#pragma unroll
      for (int nb = 0; nb < 4; ++nb) {
        float p = __expf(sc[nb][j] - mnew);
        ps += p;
        myP[(g * 4 + j) * 72 + nb * 16 + c] = f2bf(p);
      }
      ps += __shfl_xor(ps, 1);
      ps += __shfl_xor(ps, 2);
      ps += __shfl_xor(ps, 4);
      ps += __shfl_xor(ps, 8);
      lsum[j] += ps;
    }
    // PV: P from wave-private LDS (transposed read), V^T fragments from global
#pragma unroll
    for (int kc = 0; kc < 2; ++kc) {
      bf8 pa = *(const bf8*)&myP[c * 72 + kc * 32 + g * 8];
#pragma unroll
      for (int db = 0; db < 4; ++db) {
        size_t vidx = vBase + (size_t)(db * 16 + c) * S_LEN + kv0 + kc * 32 + g * 8;
        bf8 vb = *(const bf8*)&Vt[vidx];
        o[db] = __builtin_amdgcn_mfma_f32_16x16x32_bf16(pa, vb, o[db], 0, 0, 0);
      }
    }
  }
  const int b = bh >> 4, h = bh & 15;
#pragma unroll
  for (int db = 0; db < 4; ++db)
#pragma unroll
    for (int j = 0; j < 4; ++j) {
      int s = q0 + g * 4 + j;
      out[((size_t)b * S_LEN + s) * DM + h * DH + db * 16 + c] = o[db][j] / lsum[j];
    }
}

// ---------------------------------------------------------------------------
extern "C" void kernel_launch(void* const* d_in, const int* in_sizes, int n_in,
                              void* d_out, int out_size, void* d_ws, size_t ws_size,
                              hipStream_t stream) {
  const float* X    = (const float*)d_in[0];
  const float* W    = (const float*)d_in[1];
  const float* bias = (const float*)d_in[2];
  float* out = (float*)d_out;

  char* ws = (char*)d_ws;
  size_t off = 0;
  auto take = [&](size_t bytes) {
    void* p = ws + off;
    off += (bytes + 255) & ~(size_t)255;
    return p;
  };
  short* Xh  = (short*)take((size_t)NROWS * DM * 2);   // 8.4 MB
  short* Xl  = (short*)take((size_t)NROWS * DM * 2);
  short* Wth = (short*)take((size_t)EW * DM * 2);      // 6.3 MB
  short* Wtl = (short*)take((size_t)EW * DM * 2);
  short* Qh  = (short*)take((size_t)2 * NH * S_LEN * DH * 2);  // 8.4 MB each
  short* Ql  = (short*)take((size_t)2 * NH * S_LEN * DH * 2);
  short* Kh  = (short*)take((size_t)2 * NH * S_LEN * DH * 2);
  short* Kl  = (short*)take((size_t)2 * NH * S_LEN * DH * 2);
  short* Vt  = (short*)take((size_t)2 * NH * S_LEN * DH * 2);
  // total ~71.3 MB of workspace

  prep_x<<<dim3(4096), dim3(256), 0, stream>>>(X, Xh, Xl);
  prep_w<<<dim3(EW / 32, DM / 32), dim3(256), 0, stream>>>(W, Wth, Wtl);
  proj<<<dim3(NROWS / 128, EW / 128), dim3(256), 0, stream>>>(
      Xh, Xl, Wth, Wtl, bias, Qh, Ql, Kh, Kl, Vt);
  attn<<<dim3(2 * NH, S_LEN / 64), dim3(256), 0, stream>>>(
      Qh, Ql, Kh, Kl, Vt, out);
}

// Round 2
// 236.996 us; speedup vs baseline: 1.9568x; 1.9568x over previous
//
#include <hip/hip_runtime.h>

// ---------------------------------------------------------------------------
// SelfAttention: qkv = X@W + b ; per-head softmax(q k^T * sqrt(64)) @ v
// fp32 in/out. Precision: split-bf16 3-pass MFMA (hi/lo) for projection and
// Q*K^T, fp32 softmax, bf16 PV.
// v2: attn restructured — 8-wave blocks, KV staged in LDS (double-buffered,
// T14 register-staged prefetch), XOR-swizzled layout, tile-contiguous K/V.
// ---------------------------------------------------------------------------

#define S_LEN 2048
#define NH    16
#define DH    64
#define DM    1024
#define EW    3072   // NH*(64+64+64)
#define NROWS 4096   // B*S
#define NT    32     // KV tiles of 64 keys

using f32x4 = __attribute__((ext_vector_type(4))) float;
using bf8   = __attribute__((ext_vector_type(8))) short;   // 8 bf16 (4 VGPRs)
using s4v   = __attribute__((ext_vector_type(4))) short;

static __device__ __forceinline__ short f2bf(float f) {
  union { float f; unsigned u; } a; a.f = f;
  unsigned r = a.u + 0x7fffu + ((a.u >> 16) & 1u);   // RNE
  return (short)(r >> 16);
}
static __device__ __forceinline__ float bf2f(short h) {
  union { float f; unsigned u; } a;
  a.u = ((unsigned)(unsigned short)h) << 16;
  return a.f;
}
static __device__ __forceinline__ short f2bf_trunc(float f) {
  union { float f; unsigned u; } a; a.f = f;
  return (short)(a.u >> 16);
}

// --------------------------- prep: split X into bf16 hi/lo ------------------
__global__ __launch_bounds__(256) void prep_x(const float* __restrict__ X,
                                              short* __restrict__ Xh,
                                              short* __restrict__ Xl) {
  int i = blockIdx.x * 256 + threadIdx.x;              // 1,048,576 float4s
  float4 v = ((const float4*)X)[i];
  s4v h, l;
  h.x = f2bf(v.x); l.x = f2bf(v.x - bf2f(h.x));
  h.y = f2bf(v.y); l.y = f2bf(v.y - bf2f(h.y));
  h.z = f2bf(v.z); l.z = f2bf(v.z - bf2f(h.z));
  h.w = f2bf(v.w); l.w = f2bf(v.w - bf2f(h.w));
  ((s4v*)Xh)[i] = h;
  ((s4v*)Xl)[i] = l;
}

// ------------------- prep: transpose W -> W^T, split hi/lo ------------------
__global__ __launch_bounds__(256) void prep_w(const float* __restrict__ W,
                                              short* __restrict__ Wth,
                                              short* __restrict__ Wtl) {
  __shared__ float t[32][33];
  int n0 = blockIdx.x * 32;
  int k0 = blockIdx.y * 32;
  int tx = threadIdx.x & 31;
  int ty = threadIdx.x >> 5;        // 0..7
#pragma unroll
  for (int i = 0; i < 32; i += 8)
    t[ty + i][tx] = W[(size_t)(k0 + ty + i) * EW + n0 + tx];
  __syncthreads();
#pragma unroll
  for (int i = 0; i < 32; i += 8) {
    float v = t[tx][ty + i];        // k = k0+tx, n = n0+ty+i
    short hi = f2bf(v);
    short lo = f2bf(v - bf2f(hi));
    size_t o = (size_t)(n0 + ty + i) * DM + k0 + tx;
    Wth[o] = hi; Wtl[o] = lo;
  }
}

// --------------------------- projection GEMM --------------------------------
// C(4096x3072) = X(4096x1024) @ W ; 128x128 tile, 4 waves, BK=32, 3-pass MFMA.
// Epilogue scatters to Q(hi/lo, x8), K(hi/lo tile-contig), V(tile-contig d-major).
#define BK  32
#define LDKP 40   // padded LDS row stride (bf16 elems)

__global__ __launch_bounds__(256) void proj(
    const short* __restrict__ Xh, const short* __restrict__ Xl,
    const short* __restrict__ Wth, const short* __restrict__ Wtl,
    const float* __restrict__ bias,
    short* __restrict__ Qh, short* __restrict__ Ql,
    short* __restrict__ Kh, short* __restrict__ Kl,
    short* __restrict__ Vt) {
  __shared__ short Ah[128 * LDKP], Al[128 * LDKP], Bh[128 * LDKP], Bl[128 * LDKP];
  const int tid = threadIdx.x;
  const int lane = tid & 63, w = tid >> 6;
  const int wr = w >> 1, wc = w & 1;
  const int c = lane & 15, g = lane >> 4;
  const int rowBase = blockIdx.x * 128;
  const int colBase = blockIdx.y * 128;

  f32x4 acc[4][4] = {};

  const int r  = tid >> 1;           // 0..127: LDS row this thread stages
  const int k0 = (tid & 1) << 4;     // 0 or 16

  for (int kt = 0; kt < DM; kt += BK) {
    const size_t ga = (size_t)(rowBase + r) * DM + kt + k0;
    const size_t gb = (size_t)(colBase + r) * DM + kt + k0;
    *(bf8*)&Ah[r * LDKP + k0]     = *(const bf8*)&Xh[ga];
    *(bf8*)&Ah[r * LDKP + k0 + 8] = *(const bf8*)&Xh[ga + 8];
    *(bf8*)&Al[r * LDKP + k0]     = *(const bf8*)&Xl[ga];
    *(bf8*)&Al[r * LDKP + k0 + 8] = *(const bf8*)&Xl[ga + 8];
    *(bf8*)&Bh[r * LDKP + k0]     = *(const bf8*)&Wth[gb];
    *(bf8*)&Bh[r * LDKP + k0 + 8] = *(const bf8*)&Wth[gb + 8];
    *(bf8*)&Bl[r * LDKP + k0]     = *(const bf8*)&Wtl[gb];
    *(bf8*)&Bl[r * LDKP + k0 + 8] = *(const bf8*)&Wtl[gb + 8];
    __syncthreads();

    bf8 ah[4], al4[4], bh[4], bl[4];
#pragma unroll
    for (int m = 0; m < 4; ++m) {
      int ro = (wr * 64 + m * 16 + c) * LDKP + g * 8;
      ah[m]  = *(const bf8*)&Ah[ro];
      al4[m] = *(const bf8*)&Al[ro];
    }
#pragma unroll
    for (int n = 0; n < 4; ++n) {
      int ro = (wc * 64 + n * 16 + c) * LDKP + g * 8;
      bh[n] = *(const bf8*)&Bh[ro];
      bl[n] = *(const bf8*)&Bl[ro];
    }
#pragma unroll
    for (int m = 0; m < 4; ++m)
#pragma unroll
      for (int n = 0; n < 4; ++n) {
        acc[m][n] = __builtin_amdgcn_mfma_f32_16x16x32_bf16(al4[m], bh[n], acc[m][n], 0, 0, 0);
        acc[m][n] = __builtin_amdgcn_mfma_f32_16x16x32_bf16(ah[m], bl[n], acc[m][n], 0, 0, 0);
        acc[m][n] = __builtin_amdgcn_mfma_f32_16x16x32_bf16(ah[m], bh[n], acc[m][n], 0, 0, 0);
      }
    __syncthreads();
  }

  // epilogue: bias + scatter to per-head Q/K/V layouts
#pragma unroll
  for (int m = 0; m < 4; ++m)
#pragma unroll
    for (int n = 0; n < 4; ++n)
#pragma unroll
      for (int j = 0; j < 4; ++j) {
        int grow = rowBase + wr * 64 + m * 16 + g * 4 + j;   // 0..4095
        int gcol = colBase + wc * 64 + n * 16 + c;           // 0..3071
        float v = acc[m][n][j] + bias[gcol];
        int bb = grow >> 11, s = grow & 2047;
        int h = gcol / 192, e = gcol - h * 192;
        size_t hb = (size_t)(bb * NH + h);
        if (e < DH) {                      // Q: fold in the *sqrt(64) scale
          float q8 = v * 8.0f;
          short hi = f2bf(q8);
          short lo = f2bf(q8 - bf2f(hi));
          size_t idx = (hb * S_LEN + s) * DH + e;
          Qh[idx] = hi; Ql[idx] = lo;
        } else if (e < 2 * DH) {           // K: [bh][tile][row(key)][d]
          short hi = f2bf(v);
          short lo = f2bf(v - bf2f(hi));
          int tile = s >> 6, row = s & 63;
          size_t idx = ((hb * NT + tile) * (size_t)4096) + row * 64 + (e - DH);
          Kh[idx] = hi; Kl[idx] = lo;
        } else {                           // V: [bh][tile][d][key]
          int tile = s >> 6, key = s & 63;
          size_t idx = ((hb * NT + tile) * (size_t)4096) + (e - 2 * DH) * 64 + key;
          Vt[idx] = f2bf(v);
        }
      }
}

// ------------------------------ attention -----------------------------------
// grid (B*H, S/128); 8 waves per block share one bh; KV tiles staged in LDS,
// double-buffered, register-staged prefetch (T14), XOR-swizzled layout.
__global__ __launch_bounds__(512, 4) void attn(
    const short* __restrict__ Qh, const short* __restrict__ Ql,
    const short* __restrict__ KhG, const short* __restrict__ KlG,
    const short* __restrict__ VtG, float* __restrict__ out) {
  __shared__ short KHs[2][4096];   // 16 KB
  __shared__ short KLs[2][4096];   // 16 KB
  __shared__ short Vs[2][4096];    // 16 KB
  __shared__ short P[8][16 * 72];  // 18 KB, per-wave private P staging

  const int tid = threadIdx.x;
  const int lane = tid & 63, w = tid >> 6;
  const int c = lane & 15, g = lane >> 4;
  const int bh = blockIdx.x;                   // b*16 + h
  const int q0 = blockIdx.y * 128 + w * 16;
  const size_t qBase  = (size_t)bh * S_LEN * DH;
  const size_t kvBase = (size_t)bh * NT * 4096;

  // staging geometry: wave w stages rows [w*8, w*8+8) of each 64x64 tile;
  // lane covers 16B; LDS dest XOR-swizzled (slot ^= row&7).
  const int seg = w * 512 + lane * 8;          // shorts into the 8KB global tile
  const int dst = (w * 8 + (lane >> 3)) * 64 + ((((lane & 7) ^ (lane >> 3))) << 3);

  // q fragments (hi/lo), rows q0+c
  bf8 qh[2], ql[2];
#pragma unroll
  for (int kc = 0; kc < 2; ++kc) {
    size_t idx = qBase + (size_t)(q0 + c) * DH + kc * 32 + g * 8;
    qh[kc] = *(const bf8*)&Qh[idx];
    ql[kc] = *(const bf8*)&Ql[idx];
  }

  // t-invariant swizzled fragment offsets (row&7 == c&7, d&7 == c&7)
  int koff[2][4], voff[2][4];
#pragma unroll
  for (int kc = 0; kc < 2; ++kc)
#pragma unroll
    for (int i = 0; i < 4; ++i) {
      int sw = (((kc * 4 + g) ^ (c & 7)) << 3);
      koff[kc][i] = (i * 16 + c) * 64 + sw;    // i = nb (key 16-block)
      voff[kc][i] = (i * 16 + c) * 64 + sw;    // i = db (d 16-block)
    }

  float mrun[4], lsum[4];
#pragma unroll
  for (int j = 0; j < 4; ++j) { mrun[j] = -INFINITY; lsum[j] = 0.f; }
  f32x4 o[4] = {};
  short* myP = &P[w][0];

  // prologue: stage tile 0
  bf8 rkh = *(const bf8*)&KhG[kvBase + seg];
  bf8 rkl = *(const bf8*)&KlG[kvBase + seg];
  bf8 rv  = *(const bf8*)&VtG[kvBase + seg];
  *(bf8*)&KHs[0][dst] = rkh;
  *(bf8*)&KLs[0][dst] = rkl;
  *(bf8*)&Vs[0][dst]  = rv;
  __syncthreads();

  for (int t = 0; t < NT; ++t) {
    const int cur = t & 1, nxt = cur ^ 1;
    // (1) issue next tile's global loads early — latency hides under compute
    if (t + 1 < NT) {
      size_t tb = kvBase + (size_t)(t + 1) * 4096 + seg;
      rkh = *(const bf8*)&KhG[tb];
      rkl = *(const bf8*)&KlG[tb];
      rv  = *(const bf8*)&VtG[tb];
    }
    const short* KH = &KHs[cur][0];
    const short* KL = &KLs[cur][0];
    const short* VV = &Vs[cur][0];
    // (2) scores: 3-pass split-bf16
    f32x4 sc[4];
#pragma unroll
    for (int nb = 0; nb < 4; ++nb) {
      f32x4 s = {};
#pragma unroll
      for (int kc = 0; kc < 2; ++kc) {
        bf8 kh = *(const bf8*)&KH[koff[kc][nb]];
        bf8 kl = *(const bf8*)&KL[koff[kc][nb]];
        s = __builtin_amdgcn_mfma_f32_16x16x32_bf16(ql[kc], kh, s, 0, 0, 0);
        s = __builtin_amdgcn_mfma_f32_16x16x32_bf16(qh[kc], kl, s, 0, 0, 0);
        s = __builtin_amdgcn_mfma_f32_16x16x32_bf16(qh[kc], kh, s, 0, 0, 0);
      }
      sc[nb] = s;
    }
    // online softmax; lane's rows are g*4+j, col c within each 16-key block
#pragma unroll
    for (int j = 0; j < 4; ++j) {
      float t0 = fmaxf(fmaxf(sc[0][j], sc[1][j]), fmaxf(sc[2][j], sc[3][j]));
      t0 = fmaxf(t0, __shfl_xor(t0, 1));
      t0 = fmaxf(t0, __shfl_xor(t0, 2));
      t0 = fmaxf(t0, __shfl_xor(t0, 4));
      t0 = fmaxf(t0, __shfl_xor(t0, 8));
      float mnew = fmaxf(mrun[j], t0);
      float scale = __expf(mrun[j] - mnew);   // exp(-inf)=0 on first tile
      mrun[j] = mnew;
      lsum[j] *= scale;
#pragma unroll
      for (int db = 0; db < 4; ++db) o[db][j] *= scale;
      float ps = 0.f;
#pragma unroll
      for (int nb = 0; nb < 4; ++nb) {
        float p = __expf(sc[nb][j] - mnew);
        ps += p;
        myP[(g * 4 + j) * 72 + nb * 16 + c] = f2bf_trunc(p);
      }
      ps += __shfl_xor(ps, 1);
      ps += __shfl_xor(ps, 2);
      ps += __shfl_xor(ps, 4);
      ps += __shfl_xor(ps, 8);
      lsum[j] += ps;
    }
    // (3) PV: P from wave-private LDS, V fragments from swizzled LDS
#pragma unroll
    for (int kc = 0; kc < 2; ++kc) {
      bf8 pa = *(const bf8*)&myP[c * 72 + kc * 32 + g * 8];
#pragma unroll
      for (int db = 0; db < 4; ++db) {
        bf8 vb = *(const bf8*)&VV[voff[kc][db]];
        o[db] = __builtin_amdgcn_mfma_f32_16x16x32_bf16(pa, vb, o[db], 0, 0, 0);
      }
    }
    // (4) all waves done reading buf[nxt] (two barriers ago) and buf[cur]
    __syncthreads();
    if (t + 1 < NT) {
      *(bf8*)&KHs[nxt][dst] = rkh;
      *(bf8*)&KLs[nxt][dst] = rkl;
      *(bf8*)&Vs[nxt][dst]  = rv;
    }
    __syncthreads();
  }

  const int b = bh >> 4, h = bh & 15;
#pragma unroll
  for (int db = 0; db < 4; ++db)
#pragma unroll
    for (int j = 0; j < 4; ++j) {
      int s = q0 + g * 4 + j;
      out[((size_t)b * S_LEN + s) * DM + h * DH + db * 16 + c] = o[db][j] / lsum[j];
    }
}

// ---------------------------------------------------------------------------
extern "C" void kernel_launch(void* const* d_in, const int* in_sizes, int n_in,
                              void* d_out, int out_size, void* d_ws, size_t ws_size,
                              hipStream_t stream) {
  const float* X    = (const float*)d_in[0];
  const float* W    = (const float*)d_in[1];
  const float* bias = (const float*)d_in[2];
  float* out = (float*)d_out;

  char* ws = (char*)d_ws;
  size_t off = 0;
  auto take = [&](size_t bytes) {
    void* p = ws + off;
    off += (bytes + 255) & ~(size_t)255;
    return p;
  };
  short* Xh  = (short*)take((size_t)NROWS * DM * 2);   // 8.4 MB
  short* Xl  = (short*)take((size_t)NROWS * DM * 2);
  short* Wth = (short*)take((size_t)EW * DM * 2);      // 6.3 MB
  short* Wtl = (short*)take((size_t)EW * DM * 2);
  short* Qh  = (short*)take((size_t)2 * NH * S_LEN * DH * 2);  // 8.4 MB each
  short* Ql  = (short*)take((size_t)2 * NH * S_LEN * DH * 2);
  short* Kh  = (short*)take((size_t)2 * NH * NT * 4096 * 2);
  short* Kl  = (short*)take((size_t)2 * NH * NT * 4096 * 2);
  short* Vt  = (short*)take((size_t)2 * NH * NT * 4096 * 2);
  // total ~71.3 MB of workspace

  prep_x<<<dim3(4096), dim3(256), 0, stream>>>(X, Xh, Xl);
  prep_w<<<dim3(EW / 32, DM / 32), dim3(256), 0, stream>>>(W, Wth, Wtl);
  proj<<<dim3(NROWS / 128, EW / 128), dim3(256), 0, stream>>>(
      Xh, Xl, Wth, Wtl, bias, Qh, Ql, Kh, Kl, Vt);
  attn<<<dim3(2 * NH, S_LEN / 128), dim3(512), 0, stream>>>(
      Qh, Ql, Kh, Kl, Vt, out);
}

// Round 3
// 197.898 us; speedup vs baseline: 2.3433x; 1.1976x over previous
//
#include <hip/hip_runtime.h>

// ---------------------------------------------------------------------------
// SelfAttention: qkv = X@W + b ; per-head softmax(q k^T * sqrt(64)) @ v
// fp32 in/out. Precision: split-bf16 3-pass MFMA (hi/lo) for projection and
// Q*K^T, fp32 softmax (exp2 domain), bf16 PV.
// v3: proj -> global_load_lds staging + chunk-XOR swizzle (rule #21), 1 MFMA
//     cluster per K-step. attn -> 1 barrier/tile, exp2-domain softmax,
//     defer-max (T13), per-lane lsum partials, setprio (T5), XCD swizzle (T1).
// ---------------------------------------------------------------------------

#define S_LEN 2048
#define NH    16
#define DH    64
#define DM    1024
#define EW    3072   // NH*(64+64+64)
#define NROWS 4096   // B*S
#define NT    32     // KV tiles of 64 keys

// 8 * log2(e): folds the sqrt(64) score scale AND the exp->exp2 conversion
#define QSCALE 11.5415603f

using f32x4 = __attribute__((ext_vector_type(4))) float;
using bf8   = __attribute__((ext_vector_type(8))) short;   // 8 bf16 (4 VGPRs)
using s4v   = __attribute__((ext_vector_type(4))) short;

static __device__ __forceinline__ short f2bf(float f) {
  union { float f; unsigned u; } a; a.f = f;
  unsigned r = a.u + 0x7fffu + ((a.u >> 16) & 1u);   // RNE
  return (short)(r >> 16);
}
static __device__ __forceinline__ float bf2f(short h) {
  union { float f; unsigned u; } a;
  a.u = ((unsigned)(unsigned short)h) << 16;
  return a.f;
}
static __device__ __forceinline__ short f2bf_trunc(float f) {
  union { float f; unsigned u; } a; a.f = f;
  return (short)(a.u >> 16);
}
static __device__ __forceinline__ void gl16(const void* g, void* l) {
  __builtin_amdgcn_global_load_lds(
      (const __attribute__((address_space(1))) void*)g,
      (__attribute__((address_space(3))) void*)l, 16, 0, 0);
}

// --------------------------- prep: split X into bf16 hi/lo ------------------
__global__ __launch_bounds__(256) void prep_x(const float* __restrict__ X,
                                              short* __restrict__ Xh,
                                              short* __restrict__ Xl) {
  int i = blockIdx.x * 256 + threadIdx.x;              // 1,048,576 float4s
  float4 v = ((const float4*)X)[i];
  s4v h, l;
  h.x = f2bf(v.x); l.x = f2bf(v.x - bf2f(h.x));
  h.y = f2bf(v.y); l.y = f2bf(v.y - bf2f(h.y));
  h.z = f2bf(v.z); l.z = f2bf(v.z - bf2f(h.z));
  h.w = f2bf(v.w); l.w = f2bf(v.w - bf2f(h.w));
  ((s4v*)Xh)[i] = h;
  ((s4v*)Xl)[i] = l;
}

// ------------------- prep: transpose W -> W^T, split hi/lo ------------------
__global__ __launch_bounds__(256) void prep_w(const float* __restrict__ W,
                                              short* __restrict__ Wth,
                                              short* __restrict__ Wtl) {
  __shared__ float t[32][33];
  int n0 = blockIdx.x * 32;
  int k0 = blockIdx.y * 32;
  int tx = threadIdx.x & 31;
  int ty = threadIdx.x >> 5;        // 0..7
#pragma unroll
  for (int i = 0; i < 32; i += 8)
    t[ty + i][tx] = W[(size_t)(k0 + ty + i) * EW + n0 + tx];
  __syncthreads();
#pragma unroll
  for (int i = 0; i < 32; i += 8) {
    float v = t[tx][ty + i];        // k = k0+tx, n = n0+ty+i
    short hi = f2bf(v);
    short lo = f2bf(v - bf2f(hi));
    size_t o = (size_t)(n0 + ty + i) * DM + k0 + tx;
    Wth[o] = hi; Wtl[o] = lo;
  }
}

// --------------------------- projection GEMM --------------------------------
// C(4096x3072) = X(4096x1024) @ W ; 128x128 tile, 4 waves, BK=32, 3-pass MFMA.
// Staging via global_load_lds (16B), linear LDS dest + pre-swizzled global
// source chunk (^= (row>>1)&3), same XOR on the ds_read side (rule #21).
__global__ __launch_bounds__(256) void proj(
    const short* __restrict__ Xh, const short* __restrict__ Xl,
    const short* __restrict__ Wth, const short* __restrict__ Wtl,
    const float* __restrict__ bias,
    short* __restrict__ Qh, short* __restrict__ Ql,
    short* __restrict__ Kh, short* __restrict__ Kl,
    short* __restrict__ Vt) {
  __shared__ short Ah[4096], Al[4096], Bh[4096], Bl[4096];   // 8KB each, 32KB
  const int tid = threadIdx.x;
  const int lane = tid & 63, w = tid >> 6;
  const int wr = w >> 1, wc = w & 1;
  const int c = lane & 15, g = lane >> 4;

  // XCD-contiguous remap: 96 consecutive logical blocks (3 B-tiles) per XCD
  const int id = blockIdx.x;                  // 0..767
  const int lid = (id & 7) * 96 + (id >> 3);
  const int rowBase = (lid & 31) * 128;
  const int colBase = (lid >> 5) * 128;

  f32x4 acc[4][4] = {};

  // staging: wave w stages rows [32w,32w+32) as two 1KB segments per matrix.
  // lane l -> LDS row 32w + (l>>2) (+16 for seg 2), chunk l&3; the global
  // source chunk is pre-swizzled so LDS slot p holds global chunk p^f(row),
  // f(row) = (row>>1)&3  ->  here f = (l>>3)&3 for both segments.
  const int sr  = 32 * w + (lane >> 2);
  const int csw = ((lane & 3) ^ ((lane >> 3) & 3)) * 8;   // shorts
  const int ldsw = w * 1024;                              // shorts, seg base
  const size_t aBase = (size_t)(rowBase + sr) * DM + csw;
  const size_t bBase = (size_t)(colBase + sr) * DM + csw;

  // read-side swizzle: row = (16-aligned) + c  ->  f(row) = (c>>1)&3
  const int rsw = (g ^ ((c >> 1) & 3)) * 8;

  for (int kt = 0; kt < DM; kt += 32) {
    gl16(&Xh[aBase + kt],            &Ah[ldsw]);
    gl16(&Xh[aBase + kt + 16 * DM],  &Ah[ldsw + 512]);
    gl16(&Xl[aBase + kt],            &Al[ldsw]);
    gl16(&Xl[aBase + kt + 16 * DM],  &Al[ldsw + 512]);
    gl16(&Wth[bBase + kt],           &Bh[ldsw]);
    gl16(&Wth[bBase + kt + 16 * DM], &Bh[ldsw + 512]);
    gl16(&Wtl[bBase + kt],           &Bl[ldsw]);
    gl16(&Wtl[bBase + kt + 16 * DM], &Bl[ldsw + 512]);
    __syncthreads();                 // drains vmcnt: tile visible

    bf8 ah[4], al4[4], bh[4], bl[4];
#pragma unroll
    for (int m = 0; m < 4; ++m) {
      int ro = (wr * 64 + m * 16 + c) * 32 + rsw;
      ah[m]  = *(const bf8*)&Ah[ro];
      al4[m] = *(const bf8*)&Al[ro];
    }
#pragma unroll
    for (int n = 0; n < 4; ++n) {
      int ro = (wc * 64 + n * 16 + c) * 32 + rsw;
      bh[n] = *(const bf8*)&Bh[ro];
      bl[n] = *(const bf8*)&Bl[ro];
    }
    __builtin_amdgcn_s_setprio(1);
#pragma unroll
    for (int m = 0; m < 4; ++m)
#pragma unroll
      for (int n = 0; n < 4; ++n) {
        acc[m][n] = __builtin_amdgcn_mfma_f32_16x16x32_bf16(al4[m], bh[n], acc[m][n], 0, 0, 0);
        acc[m][n] = __builtin_amdgcn_mfma_f32_16x16x32_bf16(ah[m], bl[n], acc[m][n], 0, 0, 0);
        acc[m][n] = __builtin_amdgcn_mfma_f32_16x16x32_bf16(ah[m], bh[n], acc[m][n], 0, 0, 0);
      }
    __builtin_amdgcn_s_setprio(0);
    __syncthreads();                 // all reads done before next staging
  }

  // epilogue: bias + scatter to per-head Q/K/V layouts
#pragma unroll
  for (int m = 0; m < 4; ++m)
#pragma unroll
    for (int n = 0; n < 4; ++n)
#pragma unroll
      for (int j = 0; j < 4; ++j) {
        int grow = rowBase + wr * 64 + m * 16 + g * 4 + j;   // 0..4095
        int gcol = colBase + wc * 64 + n * 16 + c;           // 0..3071
        float v = acc[m][n][j] + bias[gcol];
        int bb = grow >> 11, s = grow & 2047;
        int h = gcol / 192, e = gcol - h * 192;
        size_t hb = (size_t)(bb * NH + h);
        if (e < DH) {                      // Q: fold in 8*log2e (exp2 domain)
          float q8 = v * QSCALE;
          short hi = f2bf(q8);
          short lo = f2bf(q8 - bf2f(hi));
          size_t idx = (hb * S_LEN + s) * DH + e;
          Qh[idx] = hi; Ql[idx] = lo;
        } else if (e < 2 * DH) {           // K: [bh][tile][row(key)][d]
          short hi = f2bf(v);
          short lo = f2bf(v - bf2f(hi));
          int tile = s >> 6, row = s & 63;
          size_t idx = ((hb * NT + tile) * (size_t)4096) + row * 64 + (e - DH);
          Kh[idx] = hi; Kl[idx] = lo;
        } else {                           // V: [bh][tile][d][key]
          int tile = s >> 6, key = s & 63;
          size_t idx = ((hb * NT + tile) * (size_t)4096) + (e - 2 * DH) * 64 + key;
          Vt[idx] = f2bf(v);
        }
      }
}

// ------------------------------ attention -----------------------------------
// 512 blocks (XCD-swizzled), 8 waves share one bh; KV double-buffered in LDS,
// reg-staged prefetch, ONE barrier per tile; exp2-domain online softmax with
// defer-max (THR=8 -> p<=256) and per-lane lsum partials.
__global__ __launch_bounds__(512, 4) void attn(
    const short* __restrict__ Qh, const short* __restrict__ Ql,
    const short* __restrict__ KhG, const short* __restrict__ KlG,
    const short* __restrict__ VtG, float* __restrict__ out) {
  __shared__ short KHs[2][4096];   // 16 KB
  __shared__ short KLs[2][4096];   // 16 KB
  __shared__ short Vs[2][4096];    // 16 KB
  __shared__ short P[8][16 * 72];  // 18 KB, per-wave private P staging

  const int tid = threadIdx.x;
  const int lane = tid & 63, w = tid >> 6;
  const int c = lane & 15, g = lane >> 4;
  const int id = blockIdx.x;                   // 0..511
  const int lid = (id & 7) * 64 + (id >> 3);   // 64 consecutive (4 bh) per XCD
  const int bh = lid >> 4;
  const int q0 = (lid & 15) * 128 + w * 16;
  const size_t qBase  = (size_t)bh * S_LEN * DH;
  const size_t kvBase = (size_t)bh * NT * 4096;

  // staging geometry: wave w stages rows [w*8, w*8+8); XOR-swizzled 16B slots
  const int seg = w * 512 + lane * 8;
  const int dst = (w * 8 + (lane >> 3)) * 64 + ((((lane & 7) ^ (lane >> 3))) << 3);

  bf8 qh[2], ql[2];
#pragma unroll
  for (int kc = 0; kc < 2; ++kc) {
    size_t idx = qBase + (size_t)(q0 + c) * DH + kc * 32 + g * 8;
    qh[kc] = *(const bf8*)&Qh[idx];
    ql[kc] = *(const bf8*)&Ql[idx];
  }

  int koff[2][4], voff[2][4];
#pragma unroll
  for (int kc = 0; kc < 2; ++kc)
#pragma unroll
    for (int i = 0; i < 4; ++i) {
      int sw = (((kc * 4 + g) ^ (c & 7)) << 3);
      koff[kc][i] = (i * 16 + c) * 64 + sw;
      voff[kc][i] = (i * 16 + c) * 64 + sw;
    }

  float mrun[4], lpart[4];
#pragma unroll
  for (int j = 0; j < 4; ++j) { mrun[j] = -INFINITY; lpart[j] = 0.f; }
  f32x4 o[4] = {};
  short* myP = &P[w][0];

  // prologue: stage tile 0
  {
    bf8 a = *(const bf8*)&KhG[kvBase + seg];
    bf8 b = *(const bf8*)&KlG[kvBase + seg];
    bf8 d = *(const bf8*)&VtG[kvBase + seg];
    *(bf8*)&KHs[0][dst] = a;
    *(bf8*)&KLs[0][dst] = b;
    *(bf8*)&Vs[0][dst]  = d;
  }
  __syncthreads();

  for (int t = 0; t < NT; ++t) {
    const int cur = t & 1, nxt = cur ^ 1;
    bf8 rkh, rkl, rv;
    if (t + 1 < NT) {                       // issue early; completes under compute
      size_t tb = kvBase + (size_t)(t + 1) * 4096 + seg;
      rkh = *(const bf8*)&KhG[tb];
      rkl = *(const bf8*)&KlG[tb];
      rv  = *(const bf8*)&VtG[tb];
    }
    const short* KH = &KHs[cur][0];
    const short* KL = &KLs[cur][0];
    const short* VV = &Vs[cur][0];
    // scores: 3-pass split-bf16 (log2-domain, Q pre-scaled by 8*log2e)
    f32x4 sc[4];
    __builtin_amdgcn_s_setprio(1);
#pragma unroll
    for (int nb = 0; nb < 4; ++nb) {
      f32x4 s = {};
#pragma unroll
      for (int kc = 0; kc < 2; ++kc) {
        bf8 kh = *(const bf8*)&KH[koff[kc][nb]];
        bf8 kl = *(const bf8*)&KL[koff[kc][nb]];
        s = __builtin_amdgcn_mfma_f32_16x16x32_bf16(ql[kc], kh, s, 0, 0, 0);
        s = __builtin_amdgcn_mfma_f32_16x16x32_bf16(qh[kc], kl, s, 0, 0, 0);
        s = __builtin_amdgcn_mfma_f32_16x16x32_bf16(qh[kc], kh, s, 0, 0, 0);
      }
      sc[nb] = s;
    }
    __builtin_amdgcn_s_setprio(0);
    // online softmax (exp2 domain); rows g*4+j, col c in each 16-key block
#pragma unroll
    for (int j = 0; j < 4; ++j) {
      float t0 = fmaxf(fmaxf(sc[0][j], sc[1][j]), fmaxf(sc[2][j], sc[3][j]));
      t0 = fmaxf(t0, __shfl_xor(t0, 1));
      t0 = fmaxf(t0, __shfl_xor(t0, 2));
      t0 = fmaxf(t0, __shfl_xor(t0, 4));
      t0 = fmaxf(t0, __shfl_xor(t0, 8));
      if (__any(t0 > mrun[j] + 8.0f)) {     // defer-max: p bounded by 2^8
        float mnew = fmaxf(mrun[j], t0);
        float scale = exp2f(mrun[j] - mnew);
        mrun[j] = mnew;
        lpart[j] *= scale;
        o[0][j] *= scale; o[1][j] *= scale; o[2][j] *= scale; o[3][j] *= scale;
      }
      float m = mrun[j];
      float p0 = exp2f(sc[0][j] - m), p1 = exp2f(sc[1][j] - m);
      float p2 = exp2f(sc[2][j] - m), p3 = exp2f(sc[3][j] - m);
      lpart[j] += (p0 + p1) + (p2 + p3);    // per-lane partial; reduce at end
      int pr = (g * 4 + j) * 72 + c;
      myP[pr]      = f2bf_trunc(p0);
      myP[pr + 16] = f2bf_trunc(p1);
      myP[pr + 32] = f2bf_trunc(p2);
      myP[pr + 48] = f2bf_trunc(p3);
    }
    // PV
    __builtin_amdgcn_s_setprio(1);
#pragma unroll
    for (int kc = 0; kc < 2; ++kc) {
      bf8 pa = *(const bf8*)&myP[c * 72 + kc * 32 + g * 8];
#pragma unroll
      for (int db = 0; db < 4; ++db) {
        bf8 vb = *(const bf8*)&VV[voff[kc][db]];
        o[db] = __builtin_amdgcn_mfma_f32_16x16x32_bf16(pa, vb, o[db], 0, 0, 0);
      }
    }
    __builtin_amdgcn_s_setprio(0);
    // write prefetched tile into nxt (readers only touch cur) — ONE barrier
    if (t + 1 < NT) {
      *(bf8*)&KHs[nxt][dst] = rkh;
      *(bf8*)&KLs[nxt][dst] = rkl;
      *(bf8*)&Vs[nxt][dst]  = rv;
    }
    __syncthreads();
  }

  float lsum[4];
#pragma unroll
  for (int j = 0; j < 4; ++j) {
    float s = lpart[j];
    s += __shfl_xor(s, 1);
    s += __shfl_xor(s, 2);
    s += __shfl_xor(s, 4);
    s += __shfl_xor(s, 8);
    lsum[j] = s;
  }
  const int b = bh >> 4, h = bh & 15;
#pragma unroll
  for (int db = 0; db < 4; ++db)
#pragma unroll
    for (int j = 0; j < 4; ++j) {
      int s = q0 + g * 4 + j;
      out[((size_t)b * S_LEN + s) * DM + h * DH + db * 16 + c] = o[db][j] / lsum[j];
    }
}

// ---------------------------------------------------------------------------
extern "C" void kernel_launch(void* const* d_in, const int* in_sizes, int n_in,
                              void* d_out, int out_size, void* d_ws, size_t ws_size,
                              hipStream_t stream) {
  const float* X    = (const float*)d_in[0];
  const float* W    = (const float*)d_in[1];
  const float* bias = (const float*)d_in[2];
  float* out = (float*)d_out;

  char* ws = (char*)d_ws;
  size_t off = 0;
  auto take = [&](size_t bytes) {
    void* p = ws + off;
    off += (bytes + 255) & ~(size_t)255;
    return p;
  };
  short* Xh  = (short*)take((size_t)NROWS * DM * 2);   // 8.4 MB
  short* Xl  = (short*)take((size_t)NROWS * DM * 2);
  short* Wth = (short*)take((size_t)EW * DM * 2);      // 6.3 MB
  short* Wtl = (short*)take((size_t)EW * DM * 2);
  short* Qh  = (short*)take((size_t)2 * NH * S_LEN * DH * 2);  // 8.4 MB each
  short* Ql  = (short*)take((size_t)2 * NH * S_LEN * DH * 2);
  short* Kh  = (short*)take((size_t)2 * NH * NT * 4096 * 2);
  short* Kl  = (short*)take((size_t)2 * NH * NT * 4096 * 2);
  short* Vt  = (short*)take((size_t)2 * NH * NT * 4096 * 2);
  // total ~71.3 MB of workspace

  prep_x<<<dim3(4096), dim3(256), 0, stream>>>(X, Xh, Xl);
  prep_w<<<dim3(EW / 32, DM / 32), dim3(256), 0, stream>>>(W, Wth, Wtl);
  proj<<<dim3(768), dim3(256), 0, stream>>>(
      Xh, Xl, Wth, Wtl, bias, Qh, Ql, Kh, Kl, Vt);
  attn<<<dim3(512), dim3(512), 0, stream>>>(
      Qh, Ql, Kh, Kl, Vt, out);
}